// Round 4
// baseline (36379.355 us; speedup 1.0000x reference)
//
#include <hip/hip_runtime.h>

// ShapeWeaverDecoder: 2-layer LSTM decoder, T=2048 steps, B=32, U=256.
// Round-4: same topology/protocol as r3 (256 blocks x 512 thr, checksum records
// via MALL), rescheduled for latency:
//  - joint poll: 4 loads (2 batches x data+chk), ONE vmcnt(0) -> 1-RTT poll period
//  - own-slice bypass: publisher lane pre-validates its own record locally
//  - publishes/douts drain inside subsequent polls, overlapped with foreign loads
//  - dout x-history buffered in LDS, flushed every 32 steps (no per-step stores)
// Protocol (proven r3, absmax 0.0): record = [h0..h3, chk], chk = ((((h0+h1)+h2)+h3)+tag)
// with identical rounding both sides; torn/stale reads fail validation; ring depth 2.

#define TSTEPS 2048
#define UNITS  256
#define NB     32
#define NSL    64
#define NTHR   512

typedef float f4 __attribute__((ext_vector_type(4)));

constexpr int CH   = 72;               // LDS chunk stride: conflict-free 16-way broadcast
constexpr int VECF = 4 * CH;           // one staged 256-vector (288 floats)
constexpr int BUFW = 4 * VECF;         // per-wave staging
constexpr int HIST_OFF = 8 * BUFW;     // x-history region (writer blocks only)
constexpr int SMEM_BYTES = 84 * 1024;  // force 1 block/CU
constexpr int RECF = 8;                // record stride (32B)

__device__ __forceinline__ float sigm(float x) { return 1.f / (1.f + expf(-x)); }

__device__ __forceinline__ float mk_chk(float a, float b, float c, float d, float t) {
  return __fadd_rn(__fadd_rn(__fadd_rn(__fadd_rn(a, b), c), d), t);
}

__device__ __forceinline__ void store_rec(float* p, const f4& d, float chk) {
  asm volatile("global_store_dwordx4 %0, %1, off sc0 sc1\n\t"
               "global_store_dword %0, %2, off offset:16 sc0 sc1"
               :: "v"(p), "v"(d), "v"(chk) : "memory");
}

// Both batches' records in flight together, one wait: 1-RTT poll period.
__device__ __forceinline__ void load2_rec(const float* p0, const float* p1,
                                          f4& a0, float& c0, f4& a1, float& c1) {
  asm volatile("global_load_dwordx4 %0, %4, off sc0 sc1\n\t"
               "global_load_dword %1, %4, off offset:16 sc0 sc1\n\t"
               "global_load_dwordx4 %2, %5, off sc0 sc1\n\t"
               "global_load_dword %3, %5, off offset:16 sc0 sc1\n\t"
               "s_waitcnt vmcnt(0)"
               : "=&v"(a0), "=&v"(c0), "=&v"(a1), "=&v"(c1)
               : "v"(p0), "v"(p1) : "memory");
}

__device__ __forceinline__ const float* recp(const float* ring, int k, int b, int sl) {
  return ring + (((k & 1) * NB + b) * NSL + sl) * RECF;
}

// Joint poll of 2 records; v0/v1 allow own-slice pre-validation. Bounded.
__device__ __forceinline__ bool pollj(const float* p0, const float* p1, float tag,
                                      f4& d0, f4& d1, bool v0, bool v1, bool ok) {
  if (!ok) return false;
  int it = 0;
  while (!__all(v0 && v1)) {
    f4 a0, a1; float c0, c1;
    load2_rec(p0, p1, a0, c0, a1, c1);
    if (!v0 && __float_as_uint(c0) == __float_as_uint(mk_chk(a0.x, a0.y, a0.z, a0.w, tag))) { d0 = a0; v0 = true; }
    if (!v1 && __float_as_uint(c1) == __float_as_uint(mk_chk(a1.x, a1.y, a1.z, a1.w, tag))) { d1 = a1; v1 = true; }
    if (++it > (1 << 15)) return false;
    if (it > 64) __builtin_amdgcn_s_sleep(1);
  }
  return true;
}

// Publish slice record (hn meaningful on lanes 0-3); returns the record's data
// on all lanes so the publishing lane can self-validate later polls.
__device__ __forceinline__ f4 publish(float* ring, int k, int b, int slice,
                                      int lane, float hn) {
  const float h0 = __shfl(hn, 0), h1 = __shfl(hn, 1),
              h2 = __shfl(hn, 2), h3 = __shfl(hn, 3);
  f4 d; d.x = h0; d.y = h1; d.z = h2; d.w = h3;
  if (lane == 0)
    store_rec(ring + (((k & 1) * NB + b) * NSL + slice) * RECF, d,
              mk_chk(h0, h1, h2, h3, (float)k));
  return d;
}

__global__ __launch_bounds__(NTHR) void swd_kernel(
    const float* __restrict__ ctx, const float* __restrict__ Wc, const float* __restrict__ bc,
    const float* __restrict__ K1, const float* __restrict__ R1, const float* __restrict__ b1,
    const float* __restrict__ K2, const float* __restrict__ R2, const float* __restrict__ b2,
    const float* __restrict__ Wo, const float* __restrict__ bo,
    float* __restrict__ dout, float* __restrict__ ring1, float* __restrict__ ring2)
{
  extern __shared__ float sm[];
  const int wgid  = blockIdx.x;
  const int layer = wgid >> 7;
  const int half  = (wgid >> 6) & 1;
  const int slice = wgid & 63;
  const int tid = threadIdx.x, lane = tid & 63, wid = tid >> 6;
  const int c = lane & 15, kk = lane >> 4, q = c >> 2, u = c & 3;
  const int gc = q * UNITS + slice * 4 + u;   // keras gate-major column
  const int b0 = half * 16 + wid * 2, b1v = b0 + 1;
  float* buf = sm + wid * BUFW;
  bool ok = true;

  if (layer == 0) {
    // ================= layer-1 blocks =================
    float w1[64];
    #pragma unroll
    for (int j = 0; j < 64; ++j) w1[j] = R1[(64 * kk + j) * 1024 + gc];
    const float k1a = K1[gc], k1b = K1[1024 + gc], bb1 = b1[gc];
    float wo0[4], wo1[4];
    #pragma unroll
    for (int m = 0; m < 4; ++m) {
      wo0[m] = Wo[(4 * lane + m) * 2];
      wo1[m] = Wo[(4 * lane + m) * 2 + 1];
    }
    const float bo0 = bo[0], bo1 = bo[1];
    const bool writer = (slice == 0);
    float* hist = sm + HIST_OFF + wid * 128;   // [2 batches][32 steps][2]

    // prologue: h1[0] = relu(ctx @ Wc + bc) slice -> publish tag 0
    f4 self0, self1;
    #pragma unroll
    for (int bi = 0; bi < 2; ++bi) {
      const int b = b0 + bi;
      float hn = 0.f;
      #pragma unroll
      for (int uu = 0; uu < 4; ++uu) {
        float p = 0.f;
        const float* cb = ctx + b * 512;
        const float* wc = Wc + slice * 4 + uu;
        #pragma unroll
        for (int m = 0; m < 8; ++m) p = fmaf(cb[lane * 8 + m], wc[(lane * 8 + m) * UNITS], p);
        #pragma unroll
        for (int d = 32; d; d >>= 1) p += __shfl_down(p, d);
        const float r = __shfl(p, 0);
        if (lane == uu) hn = fmaxf(r + bc[slice * 4 + uu], 0.f);
      }
      const f4 sf = publish(ring1, 0, b, slice, lane, hn);
      if (bi == 0) self0 = sf; else self1 = sf;
    }
    // stage h1[0] (own-slice bypass)
    {
      f4 d0, d1; const bool v = (lane == slice);
      if (v) { d0 = self0; d1 = self1; }
      ok = pollj(recp(ring1, 0, b0, lane), recp(ring1, 0, b1v, lane), 0.f, d0, d1, v, v, ok);
      *(f4*)(buf + kk * CH + 4 * c) = d0;
      *(f4*)(buf + VECF + kk * CH + 4 * c) = d1;
      asm volatile("" ::: "memory");
    }

    float c1a = 0.f, c1b = 0.f;   // uniform per-lane copy of unit (lane&3)'s cell state
    for (int s = 0; s < TSTEPS; ++s) {
      // R1 dots on staged h1[s] (VALU/LDS only: shadows prior store drains)
      float ax0 = 0.f, ay0 = 0.f, az0 = 0.f, aw0 = 0.f;
      float ax1 = 0.f, ay1 = 0.f, az1 = 0.f, aw1 = 0.f;
      #pragma unroll
      for (int j = 0; j < 16; ++j) {
        const f4 h0 = *(const f4*)(buf + kk * CH + 4 * j);
        const f4 h1 = *(const f4*)(buf + VECF + kk * CH + 4 * j);
        ax0 = fmaf(w1[4 * j + 0], h0.x, ax0); ay0 = fmaf(w1[4 * j + 1], h0.y, ay0);
        az0 = fmaf(w1[4 * j + 2], h0.z, az0); aw0 = fmaf(w1[4 * j + 3], h0.w, aw0);
        ax1 = fmaf(w1[4 * j + 0], h1.x, ax1); ay1 = fmaf(w1[4 * j + 1], h1.y, ay1);
        az1 = fmaf(w1[4 * j + 2], h1.z, az1); aw1 = fmaf(w1[4 * j + 3], h1.w, aw1);
      }
      float part0 = (ax0 + ay0) + (az0 + aw0);
      float part1 = (ax1 + ay1) + (az1 + aw1);
      part0 += __shfl_down(part0, 16); part0 += __shfl_down(part0, 32);
      part1 += __shfl_down(part1, 16); part1 += __shfl_down(part1, 32);

      // fresh dependency: h2[s] -> x = out[s-1]
      float x00 = 0.5f, x01 = 0.5f, x10 = 0.5f, x11 = 0.5f;
      if (s > 0) {
        f4 g0, g1;
        ok = pollj(recp(ring2, s, b0, lane), recp(ring2, s, b1v, lane), (float)s,
                   g0, g1, false, false, ok);
        float po00 = g0.x * wo0[0] + g0.y * wo0[1] + g0.z * wo0[2] + g0.w * wo0[3];
        float po01 = g0.x * wo1[0] + g0.y * wo1[1] + g0.z * wo1[2] + g0.w * wo1[3];
        float po10 = g1.x * wo0[0] + g1.y * wo0[1] + g1.z * wo0[2] + g1.w * wo0[3];
        float po11 = g1.x * wo1[0] + g1.y * wo1[1] + g1.z * wo1[2] + g1.w * wo1[3];
        #pragma unroll
        for (int d = 1; d < 64; d <<= 1) {
          po00 += __shfl_xor(po00, d); po01 += __shfl_xor(po01, d);
          po10 += __shfl_xor(po10, d); po11 += __shfl_xor(po11, d);
        }
        x00 = sigm(po00 + bo0); x01 = sigm(po01 + bo1);
        x10 = sigm(po10 + bo0); x11 = sigm(po11 + bo1);
        if (writer && lane == 0) {
          *(float2*)(hist + ((s - 1) & 31) * 2)      = make_float2(x00, x01);
          *(float2*)(hist + 64 + ((s - 1) & 31) * 2) = make_float2(x10, x11);
        }
      }

      // z1 finalize + publish (b0, then b1). Gates are shfl'd (uniform), so the
      // cell-state update is uniform across lanes; lanes 0-3 carry the real units.
      {
        const float z   = part0 + x00 * k1a + x01 * k1b + bb1;
        const float act = (q == 2) ? tanhf(z) : sigm(z);
        const float gi = __shfl(act, u),     gf = __shfl(act, 4 + u),
                    gg = __shfl(act, 8 + u), go = __shfl(act, 12 + u);
        const float cn = gf * c1a + gi * gg;
        c1a = cn;
        self0 = publish(ring1, s + 1, b0, slice, lane, go * tanhf(cn));
      }
      {
        const float z   = part1 + x10 * k1a + x11 * k1b + bb1;
        const float act = (q == 2) ? tanhf(z) : sigm(z);
        const float gi = __shfl(act, u),     gf = __shfl(act, 4 + u),
                    gg = __shfl(act, 8 + u), go = __shfl(act, 12 + u);
        const float cn = gf * c1b + gi * gg;
        c1b = cn;
        self1 = publish(ring1, s + 1, b1v, slice, lane, go * tanhf(cn));
      }

      // batched dout flush (writer blocks, every 32 steps; drains inside next poll)
      if (writer && s >= 32 && (s & 31) == 0) {
        asm volatile("" ::: "memory");
        if (lane < 16) {
          const f4 v = *(const f4*)(hist + 4 * lane);
          *(f4*)(dout + (b0 * TSTEPS + s - 32) * 2 + 4 * lane) = v;
        } else if (lane < 32) {
          const f4 v = *(const f4*)(hist + 64 + 4 * (lane - 16));
          *(f4*)(dout + (b1v * TSTEPS + s - 32) * 2 + 4 * (lane - 16)) = v;
        }
      }

      // stage h1[s+1] for next step (peers publish ~now; own-slice bypass)
      if (s < TSTEPS - 1) {
        f4 d0, d1; const bool v = (lane == slice);
        if (v) { d0 = self0; d1 = self1; }
        ok = pollj(recp(ring1, s + 1, b0, lane), recp(ring1, s + 1, b1v, lane),
                   (float)(s + 1), d0, d1, v, v, ok);
        *(f4*)(buf + kk * CH + 4 * c) = d0;
        *(f4*)(buf + VECF + kk * CH + 4 * c) = d1;
        asm volatile("" ::: "memory");
      }
    }

    // epilogue: x for t = T-1 from h2[T], then final 32-step flush
    if (writer) {
      f4 g0, g1;
      ok = pollj(recp(ring2, TSTEPS, b0, lane), recp(ring2, TSTEPS, b1v, lane),
                 (float)TSTEPS, g0, g1, false, false, ok);
      float po00 = g0.x * wo0[0] + g0.y * wo0[1] + g0.z * wo0[2] + g0.w * wo0[3];
      float po01 = g0.x * wo1[0] + g0.y * wo1[1] + g0.z * wo1[2] + g0.w * wo1[3];
      float po10 = g1.x * wo0[0] + g1.y * wo0[1] + g1.z * wo0[2] + g1.w * wo0[3];
      float po11 = g1.x * wo1[0] + g1.y * wo1[1] + g1.z * wo1[2] + g1.w * wo1[3];
      #pragma unroll
      for (int d = 1; d < 64; d <<= 1) {
        po00 += __shfl_xor(po00, d); po01 += __shfl_xor(po01, d);
        po10 += __shfl_xor(po10, d); po11 += __shfl_xor(po11, d);
      }
      if (lane == 0) {
        *(float2*)(hist + 31 * 2)      = make_float2(sigm(po00 + bo0), sigm(po01 + bo1));
        *(float2*)(hist + 64 + 31 * 2) = make_float2(sigm(po10 + bo0), sigm(po11 + bo1));
      }
      asm volatile("" ::: "memory");
      if (lane < 16) {
        const f4 v = *(const f4*)(hist + 4 * lane);
        *(f4*)(dout + (b0 * TSTEPS + TSTEPS - 32) * 2 + 4 * lane) = v;
      } else if (lane < 32) {
        const f4 v = *(const f4*)(hist + 64 + 4 * (lane - 16));
        *(f4*)(dout + (b1v * TSTEPS + TSTEPS - 32) * 2 + 4 * (lane - 16)) = v;
      }
    }
  } else {
    // ================= layer-2 blocks =================
    float wk[64], wr[64];
    #pragma unroll
    for (int j = 0; j < 64; ++j) {
      wk[j] = K2[(64 * kk + j) * 1024 + gc];
      wr[j] = R2[(64 * kk + j) * 1024 + gc];
    }
    const float bb2 = b2[gc];
    float c2a = 0.f, c2b = 0.f;
    float* bh20 = buf;
    float* bh21 = buf + VECF;
    float* bh10 = buf + 2 * VECF;
    float* bh11 = buf + 3 * VECF;
    // prologue: h2[0] = 0 staged
    {
      f4 zz; zz.x = 0.f; zz.y = 0.f; zz.z = 0.f; zz.w = 0.f;
      *(f4*)(bh20 + kk * CH + 4 * c) = zz;
      *(f4*)(bh21 + kk * CH + 4 * c) = zz;
      asm volatile("" ::: "memory");
    }
    f4 self0, self1;
    for (int s = 0; s < TSTEPS; ++s) {
      // R2 dots on staged h2[s] (shadows prior store drains)
      float rx0 = 0.f, ry0 = 0.f, rz0 = 0.f, rw0 = 0.f;
      float rx1 = 0.f, ry1 = 0.f, rz1 = 0.f, rw1 = 0.f;
      #pragma unroll
      for (int j = 0; j < 16; ++j) {
        const f4 h0 = *(const f4*)(bh20 + kk * CH + 4 * j);
        const f4 h1 = *(const f4*)(bh21 + kk * CH + 4 * j);
        rx0 = fmaf(wr[4 * j + 0], h0.x, rx0); ry0 = fmaf(wr[4 * j + 1], h0.y, ry0);
        rz0 = fmaf(wr[4 * j + 2], h0.z, rz0); rw0 = fmaf(wr[4 * j + 3], h0.w, rw0);
        rx1 = fmaf(wr[4 * j + 0], h1.x, rx1); ry1 = fmaf(wr[4 * j + 1], h1.y, ry1);
        rz1 = fmaf(wr[4 * j + 2], h1.z, rz1); rw1 = fmaf(wr[4 * j + 3], h1.w, rw1);
      }
      // fresh dependency: h1[s+1]
      {
        f4 d0, d1;
        ok = pollj(recp(ring1, s + 1, b0, lane), recp(ring1, s + 1, b1v, lane),
                   (float)(s + 1), d0, d1, false, false, ok);
        *(f4*)(bh10 + kk * CH + 4 * c) = d0;
        *(f4*)(bh11 + kk * CH + 4 * c) = d1;
        asm volatile("" ::: "memory");
      }
      float kx0 = 0.f, ky0 = 0.f, kz0 = 0.f, kw0 = 0.f;
      float kx1 = 0.f, ky1 = 0.f, kz1 = 0.f, kw1 = 0.f;
      #pragma unroll
      for (int j = 0; j < 16; ++j) {
        const f4 h0 = *(const f4*)(bh10 + kk * CH + 4 * j);
        const f4 h1 = *(const f4*)(bh11 + kk * CH + 4 * j);
        kx0 = fmaf(wk[4 * j + 0], h0.x, kx0); ky0 = fmaf(wk[4 * j + 1], h0.y, ky0);
        kz0 = fmaf(wk[4 * j + 2], h0.z, kz0); kw0 = fmaf(wk[4 * j + 3], h0.w, kw0);
        kx1 = fmaf(wk[4 * j + 0], h1.x, kx1); ky1 = fmaf(wk[4 * j + 1], h1.y, ky1);
        kz1 = fmaf(wk[4 * j + 2], h1.z, kz1); kw1 = fmaf(wk[4 * j + 3], h1.w, kw1);
      }
      float part0 = ((rx0 + ry0) + (rz0 + rw0)) + ((kx0 + ky0) + (kz0 + kw0));
      float part1 = ((rx1 + ry1) + (rz1 + rw1)) + ((kx1 + ky1) + (kz1 + kw1));
      part0 += __shfl_down(part0, 16); part0 += __shfl_down(part0, 32);
      part1 += __shfl_down(part1, 16); part1 += __shfl_down(part1, 32);
      {
        const float z   = part0 + bb2;
        const float act = (q == 2) ? tanhf(z) : sigm(z);
        const float gi = __shfl(act, u),     gf = __shfl(act, 4 + u),
                    gg = __shfl(act, 8 + u), go = __shfl(act, 12 + u);
        const float cn = gf * c2a + gi * gg;
        c2a = cn;
        self0 = publish(ring2, s + 1, b0, slice, lane, go * tanhf(cn));
      }
      {
        const float z   = part1 + bb2;
        const float act = (q == 2) ? tanhf(z) : sigm(z);
        const float gi = __shfl(act, u),     gf = __shfl(act, 4 + u),
                    gg = __shfl(act, 8 + u), go = __shfl(act, 12 + u);
        const float cn = gf * c2b + gi * gg;
        c2b = cn;
        self1 = publish(ring2, s + 1, b1v, slice, lane, go * tanhf(cn));
      }
      // stage h2[s+1] (peers publish ~now; own-slice bypass)
      if (s < TSTEPS - 1) {
        f4 d0, d1; const bool v = (lane == slice);
        if (v) { d0 = self0; d1 = self1; }
        ok = pollj(recp(ring2, s + 1, b0, lane), recp(ring2, s + 1, b1v, lane),
                   (float)(s + 1), d0, d1, v, v, ok);
        *(f4*)(bh20 + kk * CH + 4 * c) = d0;
        *(f4*)(bh21 + kk * CH + 4 * c) = d1;
        asm volatile("" ::: "memory");
      }
    }
  }
  (void)ok;
}

extern "C" void kernel_launch(void* const* d_in, const int* in_sizes, int n_in,
                              void* d_out, int out_size, void* d_ws, size_t ws_size,
                              hipStream_t stream) {
  (void)in_sizes; (void)n_in; (void)out_size; (void)ws_size;
  const float* ctx = (const float*)d_in[0];
  const float* Wc  = (const float*)d_in[1];
  const float* bc  = (const float*)d_in[2];
  const float* K1  = (const float*)d_in[3];
  const float* R1  = (const float*)d_in[4];
  const float* b1  = (const float*)d_in[5];
  const float* K2  = (const float*)d_in[6];
  const float* R2  = (const float*)d_in[7];
  const float* b2  = (const float*)d_in[8];
  const float* Wo  = (const float*)d_in[9];
  const float* bo  = (const float*)d_in[10];

  float* ring1 = (float*)d_ws;                 // [2][NB][NSL][8] = 128 KiB
  float* ring2 = ring1 + 2 * NB * NSL * RECF;  // [2][NB][NSL][8] = 128 KiB
  // No reset needed: records are self-validating (checksum+tag); poison fails
  // validation, and a previous deterministic run's leftovers are bit-identical.

  hipFuncSetAttribute((const void*)swd_kernel,
                      hipFuncAttributeMaxDynamicSharedMemorySize, SMEM_BYTES);
  swd_kernel<<<dim3(256), dim3(NTHR), SMEM_BYTES, stream>>>(
      ctx, Wc, bc, K1, R1, b1, K2, R2, b2, Wo, bo,
      (float*)d_out, ring1, ring2);
}

// Round 5
// 35812.808 us; speedup vs baseline: 1.0158x; 1.0158x over previous
//
#include <hip/hip_runtime.h>

// ShapeWeaverDecoder: 2-layer LSTM decoder, T=2048 steps, B=32, U=256.
// Round-5: batch-private islands. 256 blocks x 512 threads.
//   block (b,g): batch b = blockIdx&31, slice g = blockIdx>>5. Owns units
//   [32g,32g+32) of BOTH layers. The 8 blocks of batch b exchange h1/h2 slices
//   through MALL with the proven checksum-record protocol (r3/r4): record =
//   [h0..h3, chk], chk = ((((h0+h1)+h2)+h3)+tag) bit-identical on both sides;
//   torn/stale/poison reads fail validation; ring depth 2; no fences, no reset.
// Per block: ONE wave (wave 7) polls; wave 0 updates cell states and publishes.
// Weights in VGPRs: thread t: wA[128] = (t<256 ? R1 : K2) half-column,
// wB[64] = R2 quarter-column; h vectors broadcast from LDS (conflict-free).
// Batch chains are fully independent -> no cross-batch jitter amplification.

#define TSTEPS 2048
#define NB     32
#define NTHR   512
#define RECF   8

typedef float f4 __attribute__((ext_vector_type(4)));

__device__ __forceinline__ float sigm(float x) { return 1.f / (1.f + expf(-x)); }

__device__ __forceinline__ float mk_chk(float a, float b, float c, float d, float t) {
  return __fadd_rn(__fadd_rn(__fadd_rn(__fadd_rn(a, b), c), d), t);
}
__device__ __forceinline__ void load_rec(const float* p, f4& a, float& chk) {
  asm volatile("global_load_dwordx4 %0, %2, off sc0 sc1\n\t"
               "global_load_dword %1, %2, off offset:16 sc0 sc1\n\t"
               "s_waitcnt vmcnt(0)"
               : "=&v"(a), "=&v"(chk) : "v"(p) : "memory");
}
__device__ __forceinline__ void store_rec(float* p, const f4& d, float chk) {
  asm volatile("global_store_dwordx4 %0, %1, off sc0 sc1\n\t"
               "global_store_dword %0, %2, off offset:16 sc0 sc1"
               :: "v"(p), "v"(d), "v"(chk) : "memory");
}
__device__ __forceinline__ float* recp(float* ring, int k, int b, int idx) {
  return ring + (((k & 1) * NB + b) * 64 + idx) * RECF;
}

// Poll the 64 records of vector (k,b): lane l owns record l. Bounded.
__device__ __forceinline__ bool poll64(const float* ring, int k, int b, float tag,
                                       int lane, f4& d, bool ok) {
  if (!ok) return false;
  const float* p = ring + (((k & 1) * NB + b) * 64 + lane) * RECF;
  bool v = false;
  int it = 0;
  while (!__all(v)) {
    if (!v) {
      f4 a; float cc; load_rec(p, a, cc);
      if (__float_as_uint(cc) == __float_as_uint(mk_chk(a.x, a.y, a.z, a.w, tag))) {
        d = a; v = true;
      }
    }
    if (++it > (1 << 15)) return false;
    if (it > 64) __builtin_amdgcn_s_sleep(1);
  }
  return true;
}

__global__ __launch_bounds__(NTHR) void swd_kernel(
    const float* __restrict__ ctx, const float* __restrict__ Wc, const float* __restrict__ bc,
    const float* __restrict__ K1, const float* __restrict__ R1, const float* __restrict__ b1,
    const float* __restrict__ K2, const float* __restrict__ R2, const float* __restrict__ b2,
    const float* __restrict__ Wo, const float* __restrict__ bo,
    float* __restrict__ dout, float* __restrict__ ring1, float* __restrict__ ring2)
{
  __shared__ __align__(16) float h1buf[256];
  __shared__ __align__(16) float h2buf[256];
  __shared__ float zbuf1[256];        // [col][kh]
  __shared__ float zbuf2[1024];       // [col][8]: 0-3 R2 quarters, 4-5 K2 halves; also init scratch
  __shared__ float gbuf1[128];
  __shared__ float gbuf2[128];
  __shared__ float xbuf[2];
  __shared__ __align__(16) float hist[64];

  const int t    = threadIdx.x;
  const int wgid = blockIdx.x;
  const int b    = wgid & 31;        // batch
  const int g    = wgid >> 5;        // unit slice: sibling blocks stride 32 (same XCD under %8)
  const int lane = t & 63;
  const bool w0  = (t < 64);
  const bool w7  = (t >= 448);
  const int col  = t & 127;          // local gate-col
  const int khq  = t >> 7;           // 0..3
  const int kh   = khq & 1;
  const int q    = col >> 5;         // gate (i,f,g,o)
  const int j    = col & 31;         // unit within slice
  const int kcol = q * 256 + 32 * g + j;   // keras gate-major column

  // ---- weights into VGPRs (uniform 192 regs/thread) ----
  const float* baseA = (t < 256) ? R1 : K2;
  float wA[128], wB[64];
  #pragma unroll
  for (int m = 0; m < 128; ++m) wA[m] = baseA[(kh * 128 + m) * 1024 + kcol];
  #pragma unroll
  for (int m = 0; m < 64; ++m) wB[m] = R2[(khq * 64 + m) * 1024 + kcol];

  float k1a = 0.f, k1b = 0.f, bb1 = 0.f, bb2 = 0.f;
  if (t < 128)      { k1a = K1[kcol]; k1b = K1[1024 + kcol]; bb1 = b1[kcol]; }
  else if (t < 256) { bb2 = b2[kcol]; }
  float wo0[4], wo1[4], bo0 = 0.f, bo1 = 0.f;
  if (w7) {
    #pragma unroll
    for (int m = 0; m < 4; ++m) {
      wo0[m] = Wo[(4 * lane + m) * 2];
      wo1[m] = Wo[(4 * lane + m) * 2 + 1];
    }
    bo0 = bo[0]; bo1 = bo[1];
  }

  // ---- prologue: h1[0] slice = relu(ctx @ Wc + bc), publish tag 0, stage ----
  {
    const int jj = t & 31, kc = t >> 5;      // 16 chunks of 32
    float p = 0.f;
    #pragma unroll
    for (int m = 0; m < 32; ++m)
      p = fmaf(ctx[b * 512 + kc * 32 + m], Wc[(kc * 32 + m) * 256 + 32 * g + jj], p);
    zbuf2[kc * 32 + jj] = p;
  }
  if (t == 0) { xbuf[0] = 0.5f; xbuf[1] = 0.5f; }
  if (t < 256) h2buf[t] = 0.f;
  __syncthreads();

  bool ok = true;
  float c1 = 0.f, c2 = 0.f, hn = 0.f;
  if (t < 32) {
    float sum = bc[32 * g + t];
    #pragma unroll
    for (int kc = 0; kc < 16; ++kc) sum += zbuf2[kc * 32 + t];
    hn = fmaxf(sum, 0.f);
  }
  if (w0) {
    const float h0  = __shfl(hn, (4 * lane + 0) & 31), h1v = __shfl(hn, (4 * lane + 1) & 31),
                h2v = __shfl(hn, (4 * lane + 2) & 31), h3v = __shfl(hn, (4 * lane + 3) & 31);
    if (lane < 8) {
      f4 dd; dd.x = h0; dd.y = h1v; dd.z = h2v; dd.w = h3v;
      store_rec(recp(ring1, 0, b, g * 8 + lane), dd, mk_chk(h0, h1v, h2v, h3v, 0.f));
    }
  }
  if (w7) {
    f4 d;
    ok = poll64(ring1, 0, b, 0.f, lane, d, ok);
    *(f4*)(h1buf + 4 * lane) = d;
  }
  __syncthreads();

  // ==================== main loop ====================
  for (int s = 0; s < TSTEPS; ++s) {
    // P1: R1 half-dots on h1[s] (waves 0-3)  ||  P2: wave 7 polls h2[s] -> x
    if (t < 256) {
      float a0 = 0.f, a1 = 0.f, a2 = 0.f, a3 = 0.f;
      const f4* hp = (const f4*)(h1buf + kh * 128);
      #pragma unroll
      for (int m = 0; m < 32; ++m) {
        const f4 hv = hp[m];
        a0 = fmaf(wA[4 * m + 0], hv.x, a0);
        a1 = fmaf(wA[4 * m + 1], hv.y, a1);
        a2 = fmaf(wA[4 * m + 2], hv.z, a2);
        a3 = fmaf(wA[4 * m + 3], hv.w, a3);
      }
      zbuf1[col * 2 + kh] = (a0 + a1) + (a2 + a3);
    } else if (w7 && s > 0) {
      f4 gg;
      ok = poll64(ring2, s, b, (float)s, lane, gg, ok);
      *(f4*)(h2buf + 4 * lane) = gg;                 // lane l holds units 4l..4l+3
      float po0 = gg.x * wo0[0] + gg.y * wo0[1] + gg.z * wo0[2] + gg.w * wo0[3];
      float po1 = gg.x * wo1[0] + gg.y * wo1[1] + gg.z * wo1[2] + gg.w * wo1[3];
      #pragma unroll
      for (int dd = 1; dd < 64; dd <<= 1) { po0 += __shfl_xor(po0, dd); po1 += __shfl_xor(po1, dd); }
      const float x0 = sigm(po0 + bo0), x1 = sigm(po1 + bo1);
      if (lane == 0) {
        xbuf[0] = x0; xbuf[1] = x1;
        if (g == 0) { hist[((s - 1) & 31) * 2] = x0; hist[((s - 1) & 31) * 2 + 1] = x1; }
      }
    }
    __syncthreads();  // B1

    // P3: z1 finalize (t<128) first (critical), then R2 quarter-dots (all threads)
    if (t < 128) {
      const float z = (zbuf1[2 * t] + zbuf1[2 * t + 1]) + xbuf[0] * k1a + xbuf[1] * k1b + bb1;
      gbuf1[t] = (q == 2) ? tanhf(z) : sigm(z);
    }
    {
      float a0 = 0.f, a1 = 0.f, a2 = 0.f, a3 = 0.f;
      const f4* hp = (const f4*)(h2buf + khq * 64);
      #pragma unroll
      for (int m = 0; m < 16; ++m) {
        const f4 hv = hp[m];
        a0 = fmaf(wB[4 * m + 0], hv.x, a0);
        a1 = fmaf(wB[4 * m + 1], hv.y, a1);
        a2 = fmaf(wB[4 * m + 2], hv.z, a2);
        a3 = fmaf(wB[4 * m + 3], hv.w, a3);
      }
      zbuf2[col * 8 + khq] = (a0 + a1) + (a2 + a3);
    }
    if (w7 && g == 0 && s >= 32 && (s & 31) == 0 && lane < 16) {   // batched dout flush
      const f4 v = *(const f4*)(hist + 4 * lane);
      *(f4*)(dout + (b * TSTEPS + (s - 32)) * 2 + 4 * lane) = v;
    }
    __syncthreads();  // C

    // P4: h1 update + publish (wave 0)  ||  P5: wave 7 polls h1[s+1]
    if (t < 32) {
      const float gi = gbuf1[t], gf = gbuf1[32 + t], gG = gbuf1[64 + t], gO = gbuf1[96 + t];
      const float cn = gf * c1 + gi * gG;
      c1 = cn;
      hn = gO * tanhf(cn);
    }
    if (w0) {
      const float h0  = __shfl(hn, (4 * lane + 0) & 31), h1v = __shfl(hn, (4 * lane + 1) & 31),
                  h2v = __shfl(hn, (4 * lane + 2) & 31), h3v = __shfl(hn, (4 * lane + 3) & 31);
      if (lane < 8) {
        f4 dd; dd.x = h0; dd.y = h1v; dd.z = h2v; dd.w = h3v;
        store_rec(recp(ring1, s + 1, b, g * 8 + lane), dd,
                  mk_chk(h0, h1v, h2v, h3v, (float)(s + 1)));
      }
    }
    if (w7) {
      f4 d;
      ok = poll64(ring1, s + 1, b, (float)(s + 1), lane, d, ok);
      *(f4*)(h1buf + 4 * lane) = d;
    }
    __syncthreads();  // D

    // P6: K2 half-dots on h1[s+1] (waves 4-7)
    if (t >= 256) {
      float a0 = 0.f, a1 = 0.f, a2 = 0.f, a3 = 0.f;
      const f4* hp = (const f4*)(h1buf + kh * 128);
      #pragma unroll
      for (int m = 0; m < 32; ++m) {
        const f4 hv = hp[m];
        a0 = fmaf(wA[4 * m + 0], hv.x, a0);
        a1 = fmaf(wA[4 * m + 1], hv.y, a1);
        a2 = fmaf(wA[4 * m + 2], hv.z, a2);
        a3 = fmaf(wA[4 * m + 3], hv.w, a3);
      }
      zbuf2[col * 8 + 4 + kh] = (a0 + a1) + (a2 + a3);
    }
    __syncthreads();  // E

    // P7: z2 finalize (waves 2-3)
    if (t >= 128 && t < 256) {
      const int c = t - 128;
      const float z = ((zbuf2[c * 8 + 0] + zbuf2[c * 8 + 1]) + (zbuf2[c * 8 + 2] + zbuf2[c * 8 + 3]))
                    + (zbuf2[c * 8 + 4] + zbuf2[c * 8 + 5]) + bb2;
      gbuf2[c] = (q == 2) ? tanhf(z) : sigm(z);
    }
    __syncthreads();  // F

    // P8: h2 update + publish (wave 0, lanes 32-63)
    if (t >= 32 && t < 64) {
      const int jj = t - 32;
      const float gi = gbuf2[jj], gf = gbuf2[32 + jj], gG = gbuf2[64 + jj], gO = gbuf2[96 + jj];
      const float cn = gf * c2 + gi * gG;
      c2 = cn;
      hn = gO * tanhf(cn);
    }
    if (w0) {
      const float h0  = __shfl(hn, 32 + ((4 * lane + 0) & 31)), h1v = __shfl(hn, 32 + ((4 * lane + 1) & 31)),
                  h2v = __shfl(hn, 32 + ((4 * lane + 2) & 31)), h3v = __shfl(hn, 32 + ((4 * lane + 3) & 31));
      if (lane >= 32 && lane < 40) {
        f4 dd; dd.x = h0; dd.y = h1v; dd.z = h2v; dd.w = h3v;
        store_rec(recp(ring2, s + 1, b, g * 8 + (lane - 32)), dd,
                  mk_chk(h0, h1v, h2v, h3v, (float)(s + 1)));
      }
    }
    // no barrier: next step's B1 covers block-internal ordering
  }

  // ---- epilogue: out[T-1] from h2[T] (g==0 blocks), final 32-step flush ----
  if (g == 0 && w7) {
    f4 gg;
    ok = poll64(ring2, TSTEPS, b, (float)TSTEPS, lane, gg, ok);
    float po0 = gg.x * wo0[0] + gg.y * wo0[1] + gg.z * wo0[2] + gg.w * wo0[3];
    float po1 = gg.x * wo1[0] + gg.y * wo1[1] + gg.z * wo1[2] + gg.w * wo1[3];
    #pragma unroll
    for (int dd = 1; dd < 64; dd <<= 1) { po0 += __shfl_xor(po0, dd); po1 += __shfl_xor(po1, dd); }
    if (lane == 0) { hist[62] = sigm(po0 + bo0); hist[63] = sigm(po1 + bo1); }
    if (lane < 16) {
      const f4 v = *(const f4*)(hist + 4 * lane);
      *(f4*)(dout + (b * TSTEPS + TSTEPS - 32) * 2 + 4 * lane) = v;
    }
  }
  (void)ok;
}

extern "C" void kernel_launch(void* const* d_in, const int* in_sizes, int n_in,
                              void* d_out, int out_size, void* d_ws, size_t ws_size,
                              hipStream_t stream) {
  (void)in_sizes; (void)n_in; (void)out_size; (void)ws_size;
  const float* ctx = (const float*)d_in[0];
  const float* Wc  = (const float*)d_in[1];
  const float* bc  = (const float*)d_in[2];
  const float* K1  = (const float*)d_in[3];
  const float* R1  = (const float*)d_in[4];
  const float* b1  = (const float*)d_in[5];
  const float* K2  = (const float*)d_in[6];
  const float* R2  = (const float*)d_in[7];
  const float* b2  = (const float*)d_in[8];
  const float* Wo  = (const float*)d_in[9];
  const float* bo  = (const float*)d_in[10];

  float* ring1 = (float*)d_ws;               // [2][NB][64 recs][8] = 128 KiB
  float* ring2 = ring1 + 2 * NB * 64 * RECF; // [2][NB][64 recs][8] = 128 KiB
  // No reset: records are self-validating (checksum+tag); poison fails
  // validation; a previous deterministic run's leftovers are bit-identical.

  swd_kernel<<<dim3(256), dim3(NTHR), 0, stream>>>(
      ctx, Wc, bc, K1, R1, b1, K2, R2, b2, Wo, bo,
      (float*)d_out, ring1, ring2);
}